// Round 1
// baseline (465.149 us; speedup 1.0000x reference)
//
#include <hip/hip_runtime.h>
#include <stdint.h>

// ---------- types ----------
typedef __bf16 bf16x8 __attribute__((ext_vector_type(8)));
typedef float f32x4 __attribute__((ext_vector_type(4)));
typedef unsigned short us4_t __attribute__((ext_vector_type(4)));
typedef unsigned short us8_t __attribute__((ext_vector_type(8)));

#define LDSK 40  // 32 bf16 + 8 pad -> row stride 80B breaks 8-way bank conflict

__device__ __forceinline__ unsigned short f2bf(float f) {
  union { float f; uint32_t u; } v; v.f = f;
  uint32_t r = v.u + 0x7fffu + ((v.u >> 16) & 1u);  // RNE
  return (unsigned short)(r >> 16);
}
__device__ __forceinline__ float bf2f(unsigned short u) {
  union { uint32_t u; float f; } v; v.u = ((uint32_t)u) << 16;
  return v.f;
}

// =====================================================================
// Stage 1: h[n,o,v] = sum_c W[o,c] * x[n,v,c] + b[o]   (bf16 out)
// NT GEMM: A-op = W (rows o, c contig), B-op = x[n] (rows v, c contig)
// grid (32, 64): blockIdx.x = tm*4+tn (M=1024 -> 8 tiles, N=512 -> 4 tiles)
// =====================================================================
__global__ __launch_bounds__(256) void k_gemm1(
    const float* __restrict__ W, const float* __restrict__ X,
    const float* __restrict__ convb, unsigned short* __restrict__ H) {
  __shared__ unsigned short As[128][LDSK];
  __shared__ unsigned short Bs[128][LDSK];
  const int tid = threadIdx.x;
  const int n = blockIdx.y;
  const int tm = blockIdx.x >> 2, tn = blockIdx.x & 3;
  const float* gA = W + (size_t)tm * 128 * 512;
  const float* gB = X + ((size_t)n * 512 + tn * 128) * 512;
  const int lane = tid & 63, wid = tid >> 6;
  const int wr = (wid >> 1) * 64, wc = (wid & 1) * 64;
  const int lr = lane & 15, lk = lane >> 4;
  f32x4 acc[4][4] = {};
  for (int k0 = 0; k0 < 512; k0 += 32) {
#pragma unroll
    for (int i = 0; i < 4; ++i) {
      int s = tid + i * 256;
      int r = s >> 3, c4 = (s & 7) * 4;
      float4 fa = *(const float4*)(gA + (size_t)r * 512 + k0 + c4);
      us4_t ua = { f2bf(fa.x), f2bf(fa.y), f2bf(fa.z), f2bf(fa.w) };
      *(us4_t*)&As[r][c4] = ua;
      float4 fb = *(const float4*)(gB + (size_t)r * 512 + k0 + c4);
      us4_t ub = { f2bf(fb.x), f2bf(fb.y), f2bf(fb.z), f2bf(fb.w) };
      *(us4_t*)&Bs[r][c4] = ub;
    }
    __syncthreads();
    bf16x8 a[4], b[4];
#pragma unroll
    for (int mi = 0; mi < 4; ++mi) a[mi] = *(const bf16x8*)&As[wr + mi * 16 + lr][lk * 8];
#pragma unroll
    for (int ni = 0; ni < 4; ++ni) b[ni] = *(const bf16x8*)&Bs[wc + ni * 16 + lr][lk * 8];
#pragma unroll
    for (int mi = 0; mi < 4; ++mi)
#pragma unroll
      for (int ni = 0; ni < 4; ++ni)
        acc[mi][ni] = __builtin_amdgcn_mfma_f32_16x16x32_bf16(a[mi], b[ni], acc[mi][ni], 0, 0, 0);
    __syncthreads();
  }
  unsigned short* Hn = H + (size_t)n * 1024 * 512;
#pragma unroll
  for (int mi = 0; mi < 4; ++mi) {
#pragma unroll
    for (int i = 0; i < 4; ++i) {
      int o = tm * 128 + wr + mi * 16 + lk * 4 + i;
      float bias = convb[o];
#pragma unroll
      for (int ni = 0; ni < 4; ++ni) {
        int v = tn * 128 + wc + ni * 16 + lr;
        Hn[(size_t)o * 512 + v] = f2bf(acc[mi][ni][i] + bias);
      }
    }
  }
}

// =====================================================================
// BN stats: per channel o, mean/var over (n, v) -> scale/shift
// =====================================================================
__global__ __launch_bounds__(256) void k_bn(
    const unsigned short* __restrict__ H, const float* __restrict__ gamma,
    const float* __restrict__ beta, float* __restrict__ scale,
    float* __restrict__ shift) {
  const int o = blockIdx.x;
  const int tid = threadIdx.x;
  const int g = tid >> 6, l = tid & 63;
  float s1 = 0.f, s2 = 0.f;
  for (int step = 0; step < 16; ++step) {
    int n = g + step * 4;
    const us8_t* row = (const us8_t*)(H + ((size_t)n * 1024 + o) * 512);
    us8_t v = row[l];
#pragma unroll
    for (int j = 0; j < 8; ++j) { float f = bf2f(v[j]); s1 += f; s2 += f * f; }
  }
  __shared__ float r1[256], r2[256];
  r1[tid] = s1; r2[tid] = s2;
  __syncthreads();
  for (int off = 128; off > 0; off >>= 1) {
    if (tid < off) { r1[tid] += r1[tid + off]; r2[tid] += r2[tid + off]; }
    __syncthreads();
  }
  if (tid == 0) {
    float mean = r1[0] * (1.0f / 32768.0f);
    float var = r2[0] * (1.0f / 32768.0f) - mean * mean;
    float s = gamma[o] * rsqrtf(var + 1e-5f);
    scale[o] = s;
    shift[o] = beta[o] - mean * s;
  }
}

// =====================================================================
// Stage 2: t[nk,c,e] = sum_m BN(h)[nk,c,m] * A[nk,m,e]   (bf16 out)
// A-op = h (bf16, affine on load; rows c, m contig)
// B-op = A^T staged via in-kernel LDS transpose (A's contig dim is e)
// grid (16, 128)
// =====================================================================
__global__ __launch_bounds__(256) void k_gemm2(
    const unsigned short* __restrict__ H, const float* __restrict__ A,
    const float* __restrict__ scale, const float* __restrict__ shift,
    unsigned short* __restrict__ T) {
  __shared__ unsigned short As[128][LDSK];
  __shared__ unsigned short Bs[128][LDSK];
  const int tid = threadIdx.x;
  const int nk = blockIdx.y;
  const int kk = nk & 1, n = nk >> 1;
  const int tm = blockIdx.x >> 2, tn = blockIdx.x & 3;
  const unsigned short* gA = H + ((size_t)n * 1024 + kk * 512 + tm * 128) * 512;
  const float* gB = A + (size_t)nk * 512 * 512;  // [m][e], e contig
  const int e0 = tn * 128;
  const int ch0 = kk * 512 + tm * 128;
  const int lane = tid & 63, wid = tid >> 6;
  const int wr = (wid >> 1) * 64, wc = (wid & 1) * 64;
  const int lr = lane & 15, lk = lane >> 4;
  f32x4 acc[4][4] = {};
  for (int k0 = 0; k0 < 512; k0 += 32) {
    // A tile: bf16 load + BN affine per row
#pragma unroll
    for (int i = 0; i < 2; ++i) {
      int s = tid + i * 256;
      int r = s >> 2, c8 = (s & 3) * 8;
      us8_t v = *(const us8_t*)(gA + (size_t)r * 512 + k0 + c8);
      float sc = scale[ch0 + r], sh = shift[ch0 + r];
      us8_t w;
#pragma unroll
      for (int j = 0; j < 8; ++j) w[j] = f2bf(fmaf(bf2f(v[j]), sc, sh));
      *(us8_t*)&As[r][c8] = w;
    }
    // B tile: transpose A[m=k0..k0+31][e0..e0+127] -> Bs[e][m]
#pragma unroll
    for (int i = 0; i < 4; ++i) {
      int s = tid + i * 256;
      int ml = s >> 5;          // 0..31
      int el = (s & 31) * 4;    // 0..124
      float4 f = *(const float4*)(gB + (size_t)(k0 + ml) * 512 + e0 + el);
      Bs[el + 0][ml] = f2bf(f.x);
      Bs[el + 1][ml] = f2bf(f.y);
      Bs[el + 2][ml] = f2bf(f.z);
      Bs[el + 3][ml] = f2bf(f.w);
    }
    __syncthreads();
    bf16x8 a[4], b[4];
#pragma unroll
    for (int mi = 0; mi < 4; ++mi) a[mi] = *(const bf16x8*)&As[wr + mi * 16 + lr][lk * 8];
#pragma unroll
    for (int ni = 0; ni < 4; ++ni) b[ni] = *(const bf16x8*)&Bs[wc + ni * 16 + lr][lk * 8];
#pragma unroll
    for (int mi = 0; mi < 4; ++mi)
#pragma unroll
      for (int ni = 0; ni < 4; ++ni)
        acc[mi][ni] = __builtin_amdgcn_mfma_f32_16x16x32_bf16(a[mi], b[ni], acc[mi][ni], 0, 0, 0);
    __syncthreads();
  }
  unsigned short* Tn = T + (size_t)nk * 512 * 512;
#pragma unroll
  for (int mi = 0; mi < 4; ++mi)
#pragma unroll
    for (int i = 0; i < 4; ++i) {
      int c = tm * 128 + wr + mi * 16 + lk * 4 + i;
#pragma unroll
      for (int ni = 0; ni < 4; ++ni) {
        int e = tn * 128 + wc + ni * 16 + lr;
        Tn[(size_t)c * 512 + e] = f2bf(acc[mi][ni][i]);
      }
    }
}

// =====================================================================
// Stage 3: D[m,c] = sum_kk sum_e A[n,kk,m,e] * t[n,kk,c,e] = y[c,m]
// out[n,m,c] = (1+eps)*x[n,m,c] + D[m,c]   (coalesced row-major write)
// grid (16, 64)
// =====================================================================
__global__ __launch_bounds__(256) void k_gemm3(
    const float* __restrict__ A, const unsigned short* __restrict__ T,
    const float* __restrict__ X, const float* __restrict__ epsp,
    float* __restrict__ out) {
  __shared__ unsigned short As[128][LDSK];
  __shared__ unsigned short Bs[128][LDSK];
  const int tid = threadIdx.x;
  const int n = blockIdx.y;
  const int tm = blockIdx.x >> 2, tn = blockIdx.x & 3;
  const int lane = tid & 63, wid = tid >> 6;
  const int wr = (wid >> 1) * 64, wc = (wid & 1) * 64;
  const int lr = lane & 15, lk = lane >> 4;
  f32x4 acc[4][4] = {};
  for (int kk = 0; kk < 2; ++kk) {
    const float* gA = A + ((size_t)(n * 2 + kk) * 512 + tm * 128) * 512;          // rows m, e contig
    const unsigned short* gB = T + ((size_t)(n * 2 + kk) * 512 + tn * 128) * 512; // rows c, e contig
    for (int k0 = 0; k0 < 512; k0 += 32) {
#pragma unroll
      for (int i = 0; i < 4; ++i) {
        int s = tid + i * 256;
        int r = s >> 3, c4 = (s & 7) * 4;
        float4 f = *(const float4*)(gA + (size_t)r * 512 + k0 + c4);
        us4_t u = { f2bf(f.x), f2bf(f.y), f2bf(f.z), f2bf(f.w) };
        *(us4_t*)&As[r][c4] = u;
      }
#pragma unroll
      for (int i = 0; i < 2; ++i) {
        int s = tid + i * 256;
        int r = s >> 2, c8 = (s & 3) * 8;
        *(us8_t*)&Bs[r][c8] = *(const us8_t*)(gB + (size_t)r * 512 + k0 + c8);
      }
      __syncthreads();
      bf16x8 a[4], b[4];
#pragma unroll
      for (int mi = 0; mi < 4; ++mi) a[mi] = *(const bf16x8*)&As[wr + mi * 16 + lr][lk * 8];
#pragma unroll
      for (int ni = 0; ni < 4; ++ni) b[ni] = *(const bf16x8*)&Bs[wc + ni * 16 + lr][lk * 8];
#pragma unroll
      for (int mi = 0; mi < 4; ++mi)
#pragma unroll
        for (int ni = 0; ni < 4; ++ni)
          acc[mi][ni] = __builtin_amdgcn_mfma_f32_16x16x32_bf16(a[mi], b[ni], acc[mi][ni], 0, 0, 0);
      __syncthreads();
    }
  }
  const float e1 = 1.0f + epsp[0];
#pragma unroll
  for (int mi = 0; mi < 4; ++mi)
#pragma unroll
    for (int i = 0; i < 4; ++i) {
      int v = tm * 128 + wr + mi * 16 + lk * 4 + i;
#pragma unroll
      for (int ni = 0; ni < 4; ++ni) {
        int c = tn * 128 + wc + ni * 16 + lr;
        size_t idx = ((size_t)n * 512 + v) * 512 + c;
        out[idx] = fmaf(e1, X[idx], acc[mi][ni][i]);
      }
    }
}

// =====================================================================
// At[nk,e,m] = A[nk,m,e]  (runs LAST; region doubled as t-scratch before)
// =====================================================================
__global__ void k_at(const float* __restrict__ A, float* __restrict__ At) {
  __shared__ float tile[32][33];
  const int nk = blockIdx.z;
  const int e0 = blockIdx.x * 32, m0 = blockIdx.y * 32;
  const float* src = A + (size_t)nk * 512 * 512;
  float* dst = At + (size_t)nk * 512 * 512;
  const int tx = threadIdx.x, ty = threadIdx.y;
#pragma unroll
  for (int yy = ty; yy < 32; yy += 8)
    tile[yy][tx] = src[(size_t)(m0 + yy) * 512 + e0 + tx];
  __syncthreads();
#pragma unroll
  for (int yy = ty; yy < 32; yy += 8)
    dst[(size_t)(e0 + yy) * 512 + m0 + tx] = tile[tx][yy];
}

// =====================================================================
extern "C" void kernel_launch(void* const* d_in, const int* in_sizes, int n_in,
                              void* d_out, int out_size, void* d_ws, size_t ws_size,
                              hipStream_t stream) {
  const float* x      = (const float*)d_in[0];  // (64,512,512)
  const float* A      = (const float*)d_in[1];  // (64,2,512,512)
  const float* conv_w = (const float*)d_in[2];  // (1024,512)
  const float* conv_b = (const float*)d_in[3];  // (1024,)
  const float* gamma  = (const float*)d_in[4];  // (1024,)
  const float* beta   = (const float*)d_in[5];  // (1024,)
  const float* eps_p  = (const float*)d_in[6];  // (1,)

  float* out = (float*)d_out;                       // 16,777,216 floats
  float* At  = out + (size_t)16777216;              // 33,554,432 floats

  // Scratch lives inside d_out (every byte rewritten before final use):
  unsigned short* H = (unsigned short*)out;         // h bf16: 64*1024*512 (= out region, exact fit)
  unsigned short* T = (unsigned short*)At;          // t bf16: 64*2*512*512 (= first half of At region)
  float* scale = At + (size_t)33554432 - 2048;      // last 8KB of At region
  float* shift = scale + 1024;

  k_gemm1<<<dim3(32, 64),  256, 0, stream>>>(conv_w, x, conv_b, H);
  k_bn   <<<1024,          256, 0, stream>>>(H, gamma, beta, scale, shift);
  k_gemm2<<<dim3(16, 128), 256, 0, stream>>>(H, A, scale, shift, T);
  k_gemm3<<<dim3(16, 64),  256, 0, stream>>>(A, T, x, eps_p, out);
  k_at   <<<dim3(16, 16, 128), dim3(32, 8), 0, stream>>>(A, At);
}

// Round 2
// 352.476 us; speedup vs baseline: 1.3197x; 1.3197x over previous
//
#include <hip/hip_runtime.h>
#include <stdint.h>

// ---------- types ----------
typedef __bf16 bf16x8 __attribute__((ext_vector_type(8)));
typedef float f32x4 __attribute__((ext_vector_type(4)));
typedef unsigned short us4_t __attribute__((ext_vector_type(4)));
typedef unsigned short us8_t __attribute__((ext_vector_type(8)));

#define LDSK 40  // 32 bf16 + 8 pad -> 80B row stride

__device__ __forceinline__ unsigned short f2bf(float f) {
  __bf16 b = (__bf16)f;  // compiler emits v_cvt_pk_bf16_f32 (RNE)
  return __builtin_bit_cast(unsigned short, b);
}
__device__ __forceinline__ float bf2f(unsigned short u) {
  union { uint32_t u; float f; } v; v.u = ((uint32_t)u) << 16;
  return v.f;
}

// =====================================================================
// Stage 1: h[n,o,v] = sum_c W[o,c] * x[n,v,c] + b[o]   (bf16 out)
// NT GEMM. 1-D grid 2048 with XCD swizzle: all 32 tiles of one n share an XCD.
// =====================================================================
__global__ __launch_bounds__(256) void k_gemm1(
    const float* __restrict__ W, const float* __restrict__ X,
    const float* __restrict__ convb, unsigned short* __restrict__ H) {
  __shared__ unsigned short As[128][LDSK];
  __shared__ unsigned short Bs[128][LDSK];
  const int tid = threadIdx.x;
  const int L = blockIdx.x;
  const int xcd = L & 7, slot = L >> 3;
  const int n = xcd * 8 + (slot >> 5);
  const int tile = slot & 31;
  const int tm = tile >> 2, tn = tile & 3;
  const float* gA = W + (size_t)tm * 128 * 512;
  const float* gB = X + ((size_t)n * 512 + tn * 128) * 512;
  const int lane = tid & 63, wid = tid >> 6;
  const int wr = (wid >> 1) * 64, wc = (wid & 1) * 64;
  const int lr = lane & 15, lk = lane >> 4;
  f32x4 acc[4][4] = {};
  for (int k0 = 0; k0 < 512; k0 += 32) {
#pragma unroll
    for (int i = 0; i < 4; ++i) {
      int s = tid + i * 256;
      int r = s >> 3, c4 = (s & 7) * 4;
      float4 fa = *(const float4*)(gA + (size_t)r * 512 + k0 + c4);
      us4_t ua = { f2bf(fa.x), f2bf(fa.y), f2bf(fa.z), f2bf(fa.w) };
      *(us4_t*)&As[r][c4] = ua;
      float4 fb = *(const float4*)(gB + (size_t)r * 512 + k0 + c4);
      us4_t ub = { f2bf(fb.x), f2bf(fb.y), f2bf(fb.z), f2bf(fb.w) };
      *(us4_t*)&Bs[r][c4] = ub;
    }
    __syncthreads();
    bf16x8 a[4], b[4];
#pragma unroll
    for (int mi = 0; mi < 4; ++mi) a[mi] = *(const bf16x8*)&As[wr + mi * 16 + lr][lk * 8];
#pragma unroll
    for (int ni = 0; ni < 4; ++ni) b[ni] = *(const bf16x8*)&Bs[wc + ni * 16 + lr][lk * 8];
#pragma unroll
    for (int mi = 0; mi < 4; ++mi)
#pragma unroll
      for (int ni = 0; ni < 4; ++ni)
        acc[mi][ni] = __builtin_amdgcn_mfma_f32_16x16x32_bf16(a[mi], b[ni], acc[mi][ni], 0, 0, 0);
    __syncthreads();
  }
  unsigned short* Hn = H + (size_t)n * 1024 * 512;
#pragma unroll
  for (int mi = 0; mi < 4; ++mi) {
#pragma unroll
    for (int i = 0; i < 4; ++i) {
      int o = tm * 128 + wr + mi * 16 + lk * 4 + i;
      float bias = convb[o];
#pragma unroll
      for (int ni = 0; ni < 4; ++ni) {
        int v = tn * 128 + wc + ni * 16 + lr;
        Hn[(size_t)o * 512 + v] = f2bf(acc[mi][ni][i] + bias);
      }
    }
  }
}

// =====================================================================
// BN stats: per channel o, mean/var over (n, v) -> scale/shift
// sc_sh: [0..1024) scale, [1024..2048) shift   (lives in out region)
// =====================================================================
__global__ __launch_bounds__(256) void k_bn(
    const unsigned short* __restrict__ H, const float* __restrict__ gamma,
    const float* __restrict__ beta, float* __restrict__ sc_sh) {
  const int o = blockIdx.x;
  const int tid = threadIdx.x;
  const int g = tid >> 6, l = tid & 63;
  float s1 = 0.f, s2 = 0.f;
  for (int step = 0; step < 16; ++step) {
    int n = g + step * 4;
    const us8_t* row = (const us8_t*)(H + ((size_t)n * 1024 + o) * 512);
    us8_t v = row[l];
#pragma unroll
    for (int j = 0; j < 8; ++j) { float f = bf2f(v[j]); s1 += f; s2 += f * f; }
  }
  __shared__ float r1[256], r2[256];
  r1[tid] = s1; r2[tid] = s2;
  __syncthreads();
  for (int off = 128; off > 0; off >>= 1) {
    if (tid < off) { r1[tid] += r1[tid + off]; r2[tid] += r2[tid + off]; }
    __syncthreads();
  }
  if (tid == 0) {
    float mean = r1[0] * (1.0f / 32768.0f);
    float var = r2[0] * (1.0f / 32768.0f) - mean * mean;
    float s = gamma[o] * rsqrtf(var + 1e-5f);
    sc_sh[o] = s;
    sc_sh[1024 + o] = beta[o] - mean * s;
  }
}

// =====================================================================
// In-place BN affine over H: H[n,o,v] = H*scale[o] + shift[o]
// Each us8 touched by exactly one thread (deterministic, race-free).
// =====================================================================
__global__ __launch_bounds__(256) void k_affine(
    unsigned short* __restrict__ H, const float* __restrict__ sc_sh) {
  const size_t idx = (size_t)blockIdx.x * 256 + threadIdx.x;
  const size_t stride = (size_t)gridDim.x * 256;
  const size_t total8 = (size_t)64 * 1024 * 512 / 8;
  for (size_t i = idx; i < total8; i += stride) {
    size_t base = i * 8;
    int o = (int)((base >> 9) & 1023);
    float sc = sc_sh[o], sh = sc_sh[1024 + o];
    us8_t v = ((const us8_t*)H)[i];
    us8_t w;
#pragma unroll
    for (int j = 0; j < 8; ++j) w[j] = f2bf(fmaf(bf2f(v[j]), sc, sh));
    ((us8_t*)H)[i] = w;
  }
}

// =====================================================================
// Stage 2': B2[nk][m,m'] = sum_e A[nk][m,e] * A[nk][m',e]   (bf16 out)
// NT GEMM, both operands = rows of A (e contiguous). No LDS transpose.
// 1-D grid 2048 with XCD swizzle: 16 tiles of one nk share an XCD.
// =====================================================================
__global__ __launch_bounds__(256) void k_aat(
    const float* __restrict__ A, unsigned short* __restrict__ B2) {
  __shared__ unsigned short As[128][LDSK];
  __shared__ unsigned short Bs[128][LDSK];
  const int tid = threadIdx.x;
  const int L = blockIdx.x;
  const int xcd = L & 7, slot = L >> 3;
  const int nk = xcd * 16 + (slot >> 4);
  const int tile = slot & 15;
  const int tm = tile >> 2, tn = tile & 3;
  const float* Ank = A + (size_t)nk * 512 * 512;
  const float* gA = Ank + (size_t)tm * 128 * 512;
  const float* gB = Ank + (size_t)tn * 128 * 512;
  const int lane = tid & 63, wid = tid >> 6;
  const int wr = (wid >> 1) * 64, wc = (wid & 1) * 64;
  const int lr = lane & 15, lk = lane >> 4;
  f32x4 acc[4][4] = {};
  for (int k0 = 0; k0 < 512; k0 += 32) {
#pragma unroll
    for (int i = 0; i < 4; ++i) {
      int s = tid + i * 256;
      int r = s >> 3, c4 = (s & 7) * 4;
      float4 fa = *(const float4*)(gA + (size_t)r * 512 + k0 + c4);
      us4_t ua = { f2bf(fa.x), f2bf(fa.y), f2bf(fa.z), f2bf(fa.w) };
      *(us4_t*)&As[r][c4] = ua;
      float4 fb = *(const float4*)(gB + (size_t)r * 512 + k0 + c4);
      us4_t ub = { f2bf(fb.x), f2bf(fb.y), f2bf(fb.z), f2bf(fb.w) };
      *(us4_t*)&Bs[r][c4] = ub;
    }
    __syncthreads();
    bf16x8 a[4], b[4];
#pragma unroll
    for (int mi = 0; mi < 4; ++mi) a[mi] = *(const bf16x8*)&As[wr + mi * 16 + lr][lk * 8];
#pragma unroll
    for (int ni = 0; ni < 4; ++ni) b[ni] = *(const bf16x8*)&Bs[wc + ni * 16 + lr][lk * 8];
#pragma unroll
    for (int mi = 0; mi < 4; ++mi)
#pragma unroll
      for (int ni = 0; ni < 4; ++ni)
        acc[mi][ni] = __builtin_amdgcn_mfma_f32_16x16x32_bf16(a[mi], b[ni], acc[mi][ni], 0, 0, 0);
    __syncthreads();
  }
  unsigned short* Bn = B2 + (size_t)nk * 512 * 512;
#pragma unroll
  for (int mi = 0; mi < 4; ++mi)
#pragma unroll
    for (int i = 0; i < 4; ++i) {
      int m = tm * 128 + wr + mi * 16 + lk * 4 + i;
#pragma unroll
      for (int ni = 0; ni < 4; ++ni) {
        int mp = tn * 128 + wc + ni * 16 + lr;
        Bn[(size_t)m * 512 + mp] = f2bf(acc[mi][ni][i]);
      }
    }
}

// =====================================================================
// Stage 3': D[v,c] = sum_kk sum_m' B2[nk][v,m'] * H'[n][kk*512+c][m']
// out[n,v,c] = (1+eps)*x[n,v,c] + D[v,c]
// Both operands bf16, pure-copy staging. 1-D grid 1024 with XCD swizzle.
// =====================================================================
__global__ __launch_bounds__(256) void k_gemm3(
    const unsigned short* __restrict__ B2, const unsigned short* __restrict__ H,
    const float* __restrict__ X, const float* __restrict__ epsp,
    float* __restrict__ out) {
  __shared__ unsigned short As[128][LDSK];
  __shared__ unsigned short Bs[128][LDSK];
  const int tid = threadIdx.x;
  const int L = blockIdx.x;
  const int xcd = L & 7, slot = L >> 3;
  const int n = xcd * 8 + (slot >> 4);
  const int tile = slot & 15;
  const int tm = tile >> 2, tn = tile & 3;
  const int lane = tid & 63, wid = tid >> 6;
  const int wr = (wid >> 1) * 64, wc = (wid & 1) * 64;
  const int lr = lane & 15, lk = lane >> 4;
  f32x4 acc[4][4] = {};
  for (int kk = 0; kk < 2; ++kk) {
    const unsigned short* gA = B2 + ((size_t)(n * 2 + kk) * 512 + tm * 128) * 512; // rows v, m' contig
    const unsigned short* gB = H + ((size_t)n * 1024 + kk * 512 + tn * 128) * 512; // rows c, m' contig
    for (int k0 = 0; k0 < 512; k0 += 32) {
#pragma unroll
      for (int i = 0; i < 2; ++i) {
        int s = tid + i * 256;
        int r = s >> 2, c8 = (s & 3) * 8;
        *(us8_t*)&As[r][c8] = *(const us8_t*)(gA + (size_t)r * 512 + k0 + c8);
        *(us8_t*)&Bs[r][c8] = *(const us8_t*)(gB + (size_t)r * 512 + k0 + c8);
      }
      __syncthreads();
      bf16x8 a[4], b[4];
#pragma unroll
      for (int mi = 0; mi < 4; ++mi) a[mi] = *(const bf16x8*)&As[wr + mi * 16 + lr][lk * 8];
#pragma unroll
      for (int ni = 0; ni < 4; ++ni) b[ni] = *(const bf16x8*)&Bs[wc + ni * 16 + lr][lk * 8];
#pragma unroll
      for (int mi = 0; mi < 4; ++mi)
#pragma unroll
        for (int ni = 0; ni < 4; ++ni)
          acc[mi][ni] = __builtin_amdgcn_mfma_f32_16x16x32_bf16(a[mi], b[ni], acc[mi][ni], 0, 0, 0);
      __syncthreads();
    }
  }
  const float e1 = 1.0f + epsp[0];
#pragma unroll
  for (int mi = 0; mi < 4; ++mi)
#pragma unroll
    for (int i = 0; i < 4; ++i) {
      int v = tm * 128 + wr + mi * 16 + lk * 4 + i;
#pragma unroll
      for (int ni = 0; ni < 4; ++ni) {
        int c = tn * 128 + wc + ni * 16 + lr;
        size_t idx = ((size_t)n * 512 + v) * 512 + c;
        out[idx] = fmaf(e1, X[idx], acc[mi][ni][i]);
      }
    }
}

// =====================================================================
// At[nk,e,m] = A[nk,m,e]  (runs LAST; region was B2 + H scratch before)
// =====================================================================
__global__ void k_at(const float* __restrict__ A, float* __restrict__ At) {
  __shared__ float tile[32][33];
  const int nk = blockIdx.z;
  const int e0 = blockIdx.x * 32, m0 = blockIdx.y * 32;
  const float* src = A + (size_t)nk * 512 * 512;
  float* dst = At + (size_t)nk * 512 * 512;
  const int tx = threadIdx.x, ty = threadIdx.y;
#pragma unroll
  for (int yy = ty; yy < 32; yy += 8)
    tile[yy][tx] = src[(size_t)(m0 + yy) * 512 + e0 + tx];
  __syncthreads();
#pragma unroll
  for (int yy = ty; yy < 32; yy += 8)
    dst[(size_t)(e0 + yy) * 512 + m0 + tx] = tile[tx][yy];
}

// =====================================================================
extern "C" void kernel_launch(void* const* d_in, const int* in_sizes, int n_in,
                              void* d_out, int out_size, void* d_ws, size_t ws_size,
                              hipStream_t stream) {
  const float* x      = (const float*)d_in[0];  // (64,512,512)
  const float* A      = (const float*)d_in[1];  // (64,2,512,512)
  const float* conv_w = (const float*)d_in[2];  // (1024,512)
  const float* conv_b = (const float*)d_in[3];  // (1024,)
  const float* gamma  = (const float*)d_in[4];  // (1024,)
  const float* beta   = (const float*)d_in[5];  // (1024,)
  const float* eps_p  = (const float*)d_in[6];  // (1,)

  float* out = (float*)d_out;                       // 16,777,216 floats
  float* At  = out + (size_t)16777216;              // 33,554,432 floats

  // Scratch layout (every byte dead before its region's final write):
  //   B2 bf16 (33.5M shorts) -> At region, first half
  //   H  bf16 (33.5M shorts) -> At region, second half
  //   scale/shift (2048 f32) -> out region, start (dead before k_gemm3 writes)
  unsigned short* B2 = (unsigned short*)At;
  unsigned short* H  = (unsigned short*)(At + (size_t)16777216);
  float* sc_sh = out;

  k_gemm1 <<<2048, 256, 0, stream>>>(conv_w, x, conv_b, H);
  k_bn    <<<1024, 256, 0, stream>>>(H, gamma, beta, sc_sh);
  k_affine<<<2048, 256, 0, stream>>>(H, sc_sh);
  k_aat   <<<2048, 256, 0, stream>>>(A, B2);
  k_gemm3 <<<1024, 256, 0, stream>>>(B2, H, x, eps_p, out);
  k_at    <<<dim3(16, 16, 128), dim3(32, 8), 0, stream>>>(A, At);
}

// Round 3
// 316.308 us; speedup vs baseline: 1.4706x; 1.1143x over previous
//
#include <hip/hip_runtime.h>
#include <stdint.h>

// ---------- types ----------
typedef __bf16 bf16x8 __attribute__((ext_vector_type(8)));
typedef float f32x4 __attribute__((ext_vector_type(4)));
typedef unsigned short us4_t __attribute__((ext_vector_type(4)));
typedef unsigned short us8_t __attribute__((ext_vector_type(8)));

#define LDSK 40  // padded row (reg-staged tiles): 32 bf16 + 8 pad

__device__ __forceinline__ unsigned short f2bf(float f) {
  __bf16 b = (__bf16)f;
  return __builtin_bit_cast(unsigned short, b);
}
__device__ __forceinline__ float bf2f(unsigned short u) {
  union { uint32_t u; float f; } v; v.u = ((uint32_t)u) << 16;
  return v.f;
}

// async global->LDS, 16B per lane (wave-uniform LDS base + lane*16)
__device__ __forceinline__ void gload16(const unsigned short* g, unsigned short* l) {
  __builtin_amdgcn_global_load_lds(
      (const __attribute__((address_space(1))) void*)g,
      (__attribute__((address_space(3))) void*)l, 16, 0, 0);
}

// Stage a 128x32-short tile (linear [128][32] LDS) via 8 x global_load_lds.
// g = tile base (row 0, col 0), ldg = global row stride in shorts.
__device__ __forceinline__ void stage_tile(const unsigned short* g, size_t ldg,
                                           unsigned short* lds, int wid, int lane) {
#pragma unroll
  for (int i = 0; i < 2; ++i) {
    int seg = wid * 2 + i;  // 0..7, 16 rows each
    const unsigned short* gp = g + (size_t)(seg * 16 + (lane >> 2)) * ldg + (lane & 3) * 8;
    gload16(gp, lds + seg * 512);
  }
}

// =====================================================================
// Convert x (16.7M f32) and W (0.52M f32) to bf16 (into out region).
// =====================================================================
__global__ __launch_bounds__(256) void k_convert(
    const float* __restrict__ X, const float* __restrict__ W,
    unsigned short* __restrict__ Xb, unsigned short* __restrict__ Wb) {
  const size_t idx = (size_t)blockIdx.x * 256 + threadIdx.x;
  const size_t stride = (size_t)gridDim.x * 256;
  for (size_t i = idx; i < (size_t)16777216 / 8; i += stride) {
    float4 f0 = ((const float4*)X)[2 * i], f1 = ((const float4*)X)[2 * i + 1];
    us8_t w = { f2bf(f0.x), f2bf(f0.y), f2bf(f0.z), f2bf(f0.w),
                f2bf(f1.x), f2bf(f1.y), f2bf(f1.z), f2bf(f1.w) };
    ((us8_t*)Xb)[i] = w;
  }
  for (size_t i = idx; i < (size_t)524288 / 8; i += stride) {
    float4 f0 = ((const float4*)W)[2 * i], f1 = ((const float4*)W)[2 * i + 1];
    us8_t w = { f2bf(f0.x), f2bf(f0.y), f2bf(f0.z), f2bf(f0.w),
                f2bf(f1.x), f2bf(f1.y), f2bf(f1.z), f2bf(f1.w) };
    ((us8_t*)Wb)[i] = w;
  }
}

// =====================================================================
// Stage 1: h[n,o,v] = sum_c W[o,c]*x[n,v,c] + b[o]  (bf16 out, raw h)
// Both operands bf16 -> global_load_lds staging, linear [128][32] LDS.
// =====================================================================
__global__ __launch_bounds__(256) void k_gemm1(
    const unsigned short* __restrict__ Wb, const unsigned short* __restrict__ Xb,
    const float* __restrict__ convb, unsigned short* __restrict__ H) {
  __shared__ unsigned short As[128][32];
  __shared__ unsigned short Bs[128][32];
  const int tid = threadIdx.x;
  const int L = blockIdx.x;
  const int xcd = L & 7, slot = L >> 3;
  const int n = xcd * 8 + (slot >> 5);
  const int tile = slot & 31;
  const int tm = tile >> 2, tn = tile & 3;
  const unsigned short* gA = Wb + (size_t)tm * 128 * 512;
  const unsigned short* gB = Xb + ((size_t)n * 512 + tn * 128) * 512;
  const int lane = tid & 63, wid = tid >> 6;
  const int wr = (wid >> 1) * 64, wc = (wid & 1) * 64;
  const int lr = lane & 15, lk = lane >> 4;
  f32x4 acc[4][4] = {};
  for (int k0 = 0; k0 < 512; k0 += 32) {
    stage_tile(gA + k0, 512, &As[0][0], wid, lane);
    stage_tile(gB + k0, 512, &Bs[0][0], wid, lane);
    __syncthreads();
    bf16x8 a[4], b[4];
#pragma unroll
    for (int mi = 0; mi < 4; ++mi) a[mi] = *(const bf16x8*)&As[wr + mi * 16 + lr][lk * 8];
#pragma unroll
    for (int ni = 0; ni < 4; ++ni) b[ni] = *(const bf16x8*)&Bs[wc + ni * 16 + lr][lk * 8];
#pragma unroll
    for (int mi = 0; mi < 4; ++mi)
#pragma unroll
      for (int ni = 0; ni < 4; ++ni)
        acc[mi][ni] = __builtin_amdgcn_mfma_f32_16x16x32_bf16(a[mi], b[ni], acc[mi][ni], 0, 0, 0);
    __syncthreads();
  }
  unsigned short* Hn = H + (size_t)n * 1024 * 512;
#pragma unroll
  for (int mi = 0; mi < 4; ++mi)
#pragma unroll
    for (int i = 0; i < 4; ++i) {
      int o = tm * 128 + wr + mi * 16 + lk * 4 + i;
      float bias = convb[o];
#pragma unroll
      for (int ni = 0; ni < 4; ++ni) {
        int v = tn * 128 + wc + ni * 16 + lr;
        Hn[(size_t)o * 512 + v] = f2bf(acc[mi][ni][i] + bias);
      }
    }
}

// =====================================================================
// BN stats from raw H -> scale/shift
// =====================================================================
__global__ __launch_bounds__(256) void k_bn(
    const unsigned short* __restrict__ H, const float* __restrict__ gamma,
    const float* __restrict__ beta, float* __restrict__ sc_sh) {
  const int o = blockIdx.x;
  const int tid = threadIdx.x;
  const int g = tid >> 6, l = tid & 63;
  float s1 = 0.f, s2 = 0.f;
  for (int step = 0; step < 16; ++step) {
    int n = g + step * 4;
    const us8_t* row = (const us8_t*)(H + ((size_t)n * 1024 + o) * 512);
    us8_t v = row[l];
#pragma unroll
    for (int j = 0; j < 8; ++j) { float f = bf2f(v[j]); s1 += f; s2 += f * f; }
  }
  __shared__ float r1[256], r2[256];
  r1[tid] = s1; r2[tid] = s2;
  __syncthreads();
  for (int off = 128; off > 0; off >>= 1) {
    if (tid < off) { r1[tid] += r1[tid + off]; r2[tid] += r2[tid + off]; }
    __syncthreads();
  }
  if (tid == 0) {
    float mean = r1[0] * (1.0f / 32768.0f);
    float var = r2[0] * (1.0f / 32768.0f) - mean * mean;
    float s = gamma[o] * rsqrtf(var + 1e-5f);
    sc_sh[o] = s;
    sc_sh[1024 + o] = beta[o] - mean * s;
  }
}

// =====================================================================
// Fallback only (ws too small): in-place affine on H.
// =====================================================================
__global__ __launch_bounds__(256) void k_affine(
    unsigned short* __restrict__ H, const float* __restrict__ sc_sh) {
  const size_t idx = (size_t)blockIdx.x * 256 + threadIdx.x;
  const size_t stride = (size_t)gridDim.x * 256;
  const size_t total8 = (size_t)64 * 1024 * 512 / 8;
  for (size_t i = idx; i < total8; i += stride) {
    size_t base = i * 8;
    int o = (int)((base >> 9) & 1023);
    float sc = sc_sh[o], sh = sc_sh[1024 + o];
    us8_t v = ((const us8_t*)H)[i];
    us8_t w;
#pragma unroll
    for (int j = 0; j < 8; ++j) w[j] = f2bf(fmaf(bf2f(v[j]), sc, sh));
    ((us8_t*)H)[i] = w;
  }
}

// =====================================================================
// Stage 2': B2[nk][m,m'] = sum_e A[m,e]*A[m',e]  (fp32 in, reg-staged)
// =====================================================================
__global__ __launch_bounds__(256) void k_aat(
    const float* __restrict__ A, unsigned short* __restrict__ B2) {
  __shared__ unsigned short As[128][LDSK];
  __shared__ unsigned short Bs[128][LDSK];
  const int tid = threadIdx.x;
  const int L = blockIdx.x;
  const int xcd = L & 7, slot = L >> 3;
  const int nk = xcd * 16 + (slot >> 4);
  const int tile = slot & 15;
  const int tm = tile >> 2, tn = tile & 3;
  const float* Ank = A + (size_t)nk * 512 * 512;
  const float* gA = Ank + (size_t)tm * 128 * 512;
  const float* gB = Ank + (size_t)tn * 128 * 512;
  const int lane = tid & 63, wid = tid >> 6;
  const int wr = (wid >> 1) * 64, wc = (wid & 1) * 64;
  const int lr = lane & 15, lk = lane >> 4;
  f32x4 acc[4][4] = {};
  for (int k0 = 0; k0 < 512; k0 += 32) {
#pragma unroll
    for (int i = 0; i < 4; ++i) {
      int s = tid + i * 256;
      int r = s >> 3, c4 = (s & 7) * 4;
      float4 fa = *(const float4*)(gA + (size_t)r * 512 + k0 + c4);
      us4_t ua = { f2bf(fa.x), f2bf(fa.y), f2bf(fa.z), f2bf(fa.w) };
      *(us4_t*)&As[r][c4] = ua;
      float4 fb = *(const float4*)(gB + (size_t)r * 512 + k0 + c4);
      us4_t ub = { f2bf(fb.x), f2bf(fb.y), f2bf(fb.z), f2bf(fb.w) };
      *(us4_t*)&Bs[r][c4] = ub;
    }
    __syncthreads();
    bf16x8 a[4], b[4];
#pragma unroll
    for (int mi = 0; mi < 4; ++mi) a[mi] = *(const bf16x8*)&As[wr + mi * 16 + lr][lk * 8];
#pragma unroll
    for (int ni = 0; ni < 4; ++ni) b[ni] = *(const bf16x8*)&Bs[wc + ni * 16 + lr][lk * 8];
#pragma unroll
    for (int mi = 0; mi < 4; ++mi)
#pragma unroll
      for (int ni = 0; ni < 4; ++ni)
        acc[mi][ni] = __builtin_amdgcn_mfma_f32_16x16x32_bf16(a[mi], b[ni], acc[mi][ni], 0, 0, 0);
    __syncthreads();
  }
  unsigned short* Bn = B2 + (size_t)nk * 512 * 512;
#pragma unroll
  for (int mi = 0; mi < 4; ++mi)
#pragma unroll
    for (int i = 0; i < 4; ++i) {
      int m = tm * 128 + wr + mi * 16 + lk * 4 + i;
#pragma unroll
      for (int ni = 0; ni < 4; ++ni) {
        int mp = tn * 128 + wc + ni * 16 + lr;
        Bn[(size_t)m * 512 + mp] = f2bf(acc[mi][ni][i]);
      }
    }
}

// =====================================================================
// Stage 3': out[n,v,c] = (1+eps)*x + sum_kk sum_m' B2[nk][v,m'] * h'[o,m']
// A-op (B2) via global_load_lds; B-op (H) reg-staged with affine folded.
// =====================================================================
template <bool AFFINE>
__global__ __launch_bounds__(256) void k_gemm3(
    const unsigned short* __restrict__ B2, const unsigned short* __restrict__ H,
    const float* __restrict__ sc_sh, const float* __restrict__ X,
    const float* __restrict__ epsp, float* __restrict__ out) {
  __shared__ unsigned short As[128][32];    // linear: global_load_lds dest
  __shared__ unsigned short Bs[128][LDSK];  // padded: reg-staged
  __shared__ float s_sc[2][128], s_sh[2][128];
  const int tid = threadIdx.x;
  const int L = blockIdx.x;
  const int xcd = L & 7, slot = L >> 3;
  const int n = xcd * 8 + (slot >> 4);
  const int tile = slot & 15;
  const int tm = tile >> 2, tn = tile & 3;
  const int lane = tid & 63, wid = tid >> 6;
  const int wr = (wid >> 1) * 64, wc = (wid & 1) * 64;
  const int lr = lane & 15, lk = lane >> 4;
  if (AFFINE) {
    if (tid < 256) {
      int kkq = tid >> 7, r = tid & 127;
      s_sc[kkq][r] = sc_sh[kkq * 512 + tn * 128 + r];
      s_sh[kkq][r] = sc_sh[1024 + kkq * 512 + tn * 128 + r];
    }
    __syncthreads();
  }
  f32x4 acc[4][4] = {};
  for (int kk = 0; kk < 2; ++kk) {
    const unsigned short* gA = B2 + ((size_t)(n * 2 + kk) * 512 + tm * 128) * 512;
    const unsigned short* gB = H + ((size_t)n * 1024 + kk * 512 + tn * 128) * 512;
    for (int k0 = 0; k0 < 512; k0 += 32) {
      stage_tile(gA + k0, 512, &As[0][0], wid, lane);  // async, in flight during Bs staging
#pragma unroll
      for (int i = 0; i < 2; ++i) {
        int s = tid + i * 256;
        int r = s >> 2, c8 = (s & 3) * 8;
        us8_t v = *(const us8_t*)(gB + (size_t)r * 512 + k0 + c8);
        if (AFFINE) {
          float sc = s_sc[kk][r], sh = s_sh[kk][r];
          us8_t w;
#pragma unroll
          for (int j = 0; j < 8; ++j) w[j] = f2bf(fmaf(bf2f(v[j]), sc, sh));
          *(us8_t*)&Bs[r][c8] = w;
        } else {
          *(us8_t*)&Bs[r][c8] = v;
        }
      }
      __syncthreads();
      bf16x8 a[4], b[4];
#pragma unroll
      for (int mi = 0; mi < 4; ++mi) a[mi] = *(const bf16x8*)&As[wr + mi * 16 + lr][lk * 8];
#pragma unroll
      for (int ni = 0; ni < 4; ++ni) b[ni] = *(const bf16x8*)&Bs[wc + ni * 16 + lr][lk * 8];
#pragma unroll
      for (int mi = 0; mi < 4; ++mi)
#pragma unroll
        for (int ni = 0; ni < 4; ++ni)
          acc[mi][ni] = __builtin_amdgcn_mfma_f32_16x16x32_bf16(a[mi], b[ni], acc[mi][ni], 0, 0, 0);
      __syncthreads();
    }
  }
  const float e1 = 1.0f + epsp[0];
#pragma unroll
  for (int mi = 0; mi < 4; ++mi)
#pragma unroll
    for (int i = 0; i < 4; ++i) {
      int v = tm * 128 + wr + mi * 16 + lk * 4 + i;
#pragma unroll
      for (int ni = 0; ni < 4; ++ni) {
        int c = tn * 128 + wc + ni * 16 + lr;
        size_t idx = ((size_t)n * 512 + v) * 512 + c;
        out[idx] = fmaf(e1, X[idx], acc[mi][ni][i]);
      }
    }
}

// =====================================================================
// At[nk,e,m] = A[nk,m,e]  (runs LAST)
// =====================================================================
__global__ void k_at(const float* __restrict__ A, float* __restrict__ At) {
  __shared__ float tile[32][33];
  const int nk = blockIdx.z;
  const int e0 = blockIdx.x * 32, m0 = blockIdx.y * 32;
  const float* src = A + (size_t)nk * 512 * 512;
  float* dst = At + (size_t)nk * 512 * 512;
  const int tx = threadIdx.x, ty = threadIdx.y;
#pragma unroll
  for (int yy = ty; yy < 32; yy += 8)
    tile[yy][tx] = src[(size_t)(m0 + yy) * 512 + e0 + tx];
  __syncthreads();
#pragma unroll
  for (int yy = ty; yy < 32; yy += 8)
    dst[(size_t)(e0 + yy) * 512 + m0 + tx] = tile[tx][yy];
}

// =====================================================================
extern "C" void kernel_launch(void* const* d_in, const int* in_sizes, int n_in,
                              void* d_out, int out_size, void* d_ws, size_t ws_size,
                              hipStream_t stream) {
  const float* x      = (const float*)d_in[0];  // (64,512,512)
  const float* A      = (const float*)d_in[1];  // (64,2,512,512)
  const float* conv_w = (const float*)d_in[2];  // (1024,512)
  const float* conv_b = (const float*)d_in[3];  // (1024,)
  const float* gamma  = (const float*)d_in[4];  // (1024,)
  const float* beta   = (const float*)d_in[5];  // (1024,)
  const float* eps_p  = (const float*)d_in[6];  // (1,)

  float* out = (float*)d_out;           // 16,777,216 floats
  float* At  = out + (size_t)16777216;  // 33,554,432 floats

  // Scratch (all inside d_out, every byte dead before its final write):
  //   At region: B2 bf16 [0..33.5M shorts) | H bf16 [33.5M..67M shorts)
  //   out region: x_bf16 [0..16.7M shorts) | W_bf16 [16.7M..17.3M shorts)
  //               (both dead after k_gemm1; out written only by k_gemm3)
  unsigned short* B2 = (unsigned short*)At;
  unsigned short* H  = (unsigned short*)(At + (size_t)16777216);
  unsigned short* Xb = (unsigned short*)out;
  unsigned short* Wb = Xb + (size_t)16777216;

  const bool use_ws = (ws_size >= 8192);
  // main path: sc_sh in d_ws (gemm3 reads it while writing out -> must not alias out)
  // fallback: sc_sh at start of out region (dead x_bf16 space), affine as its own pass
  float* sc_sh = use_ws ? (float*)d_ws : out;

  k_convert<<<2048, 256, 0, stream>>>(x, conv_w, Xb, Wb);
  k_gemm1  <<<2048, 256, 0, stream>>>(Wb, Xb, conv_b, H);
  k_bn     <<<1024, 256, 0, stream>>>(H, gamma, beta, sc_sh);
  k_aat    <<<2048, 256, 0, stream>>>(A, B2);
  if (use_ws) {
    k_gemm3<true><<<1024, 256, 0, stream>>>(B2, H, sc_sh, x, eps_p, out);
  } else {
    k_affine<<<2048, 256, 0, stream>>>(H, sc_sh);
    k_gemm3<false><<<1024, 256, 0, stream>>>(B2, H, nullptr, x, eps_p, out);
  }
  k_at<<<dim3(16, 16, 128), dim3(32, 8), 0, stream>>>(A, At);
}